// Round 1
// baseline (163.263 us; speedup 1.0000x reference)
//
#include <hip/hip_runtime.h>
#include <cstddef>

#define HWT   3136        // 56*56
#define WIMG  56
#define CCH   256
#define NH    8
#define QKV_ELEMS (16 * HWT * 32)   // per-tensor q/k/v elements = 1,605,632
#define SCALE 0.17677669529663687f  // 32^-0.5

// ---------------------------------------------------------------------------
// Kernel 0: build the scrambled-gather source table.
// Reference does unfold(...).reshape(B,C,L,49) which REINTERPRETS the
// (C,49,2500) patch block as (C,2500,49). For l in [0,2500), k in [0,49):
//   f = l*49 + k; s = f/2500 (patch offset); pos = f%2500 (patch origin)
//   src pixel = (pos/50 + s/7, pos%50 + s%7) in the 56x56 image.
// ---------------------------------------------------------------------------
__global__ __launch_bounds__(256) void build_src_k(int* __restrict__ src) {
  int e = blockIdx.x * 256 + threadIdx.x;
  if (e >= 2500 * 49) return;
  int s = e / 2500;
  int pos = e % 2500;
  int i = pos / 50 + s / 7;
  int j = pos % 50 + s % 7;
  src[e] = i * WIMG + j;
}

// ---------------------------------------------------------------------------
// fp32 tiled GEMM: Out[o,hw] = sum_c A[o,c] * X[b,c,hw] + bias[o]
// 128x128 tile, BK=8, 256 threads, 8x8 micro-tile per thread.
// MODE 0: qkv — scatter into q/k/v tensors laid out (b, n, hw, d), q scaled.
// MODE 1: proj — store to d_out as (b, o, hw).
// ---------------------------------------------------------------------------
template <int MODE>
__global__ __launch_bounds__(256) void gemm_k(
    const float* __restrict__ A, const float* __restrict__ bias,
    const float* __restrict__ X, float* __restrict__ Out) {
  __shared__ float As[8][128];   // [kk][m]
  __shared__ float Bs[8][128];   // [kk][n]

  const int tid = threadIdx.x;
  const int tx = tid & 15, ty = tid >> 4;
  const int n0 = blockIdx.x * 128;
  const int m0 = blockIdx.y * 128;
  const int b  = blockIdx.z;

  const float* Xb = X + (size_t)b * CCH * HWT;

  const int arow = tid >> 1, akc = (tid & 1) * 4;   // A: 2 thr/row, float4 in k
  const int brow = tid >> 5, bcol = (tid & 31) * 4; // B: 32 thr/row, float4 in n
  const int gn = n0 + bcol;                         // HWT%4==0, no straddle

  float acc[8][8];
#pragma unroll
  for (int i = 0; i < 8; ++i)
#pragma unroll
    for (int j = 0; j < 8; ++j) acc[i][j] = 0.f;

  for (int k0 = 0; k0 < CCH; k0 += 8) {
    float4 av = *(const float4*)(A + (size_t)(m0 + arow) * CCH + k0 + akc);
    float4 bv = make_float4(0.f, 0.f, 0.f, 0.f);
    if (gn < HWT) bv = *(const float4*)(Xb + (size_t)(k0 + brow) * HWT + gn);
    __syncthreads();
    As[akc + 0][arow] = av.x;
    As[akc + 1][arow] = av.y;
    As[akc + 2][arow] = av.z;
    As[akc + 3][arow] = av.w;
    *(float4*)&Bs[brow][bcol] = bv;
    __syncthreads();
#pragma unroll
    for (int kk = 0; kk < 8; ++kk) {
      float a[8], bb[8];
      *(float4*)&a[0]  = *(const float4*)&As[kk][ty * 8];
      *(float4*)&a[4]  = *(const float4*)&As[kk][ty * 8 + 4];
      *(float4*)&bb[0] = *(const float4*)&Bs[kk][tx * 8];
      *(float4*)&bb[4] = *(const float4*)&Bs[kk][tx * 8 + 4];
#pragma unroll
      for (int i = 0; i < 8; ++i)
#pragma unroll
        for (int j = 0; j < 8; ++j) acc[i][j] += a[i] * bb[j];
    }
  }

#pragma unroll
  for (int i = 0; i < 8; ++i) {
    const int o = m0 + ty * 8 + i;
    const float bo = bias[o];
#pragma unroll
    for (int j = 0; j < 8; ++j) {
      const int hw = n0 + tx * 8 + j;
      if (hw >= HWT) continue;
      float val = acc[i][j] + bo;
      if (MODE == 0) {
        const int t = o >> 8, c = o & 255;           // t: 0=q 1=k 2=v
        if (t == 0) val *= SCALE;
        Out[(size_t)t * QKV_ELEMS +
            ((size_t)(b * NH + (c >> 5)) * HWT + hw) * 32 + (c & 31)] = val;
      } else {
        Out[((size_t)b * CCH + o) * HWT + hw] = val;
      }
    }
  }
}

// ---------------------------------------------------------------------------
// Attention: no softmax. att[b,c,hw] = sum_k (q.k_src + bias) * v_src
// 4 threads per pixel (dp = quarter of hd=32); dot reduced via shfl_xor(1,2).
// Block = 256 thr = 4 rows x 16 cols of pixels; grid = 16 bn * 14 * 4.
// ---------------------------------------------------------------------------
__global__ __launch_bounds__(256) void attn_k(
    const float* __restrict__ q, const float* __restrict__ kt,
    const float* __restrict__ vt, const int* __restrict__ src,
    const float* __restrict__ relbias, float* __restrict__ att) {
  const int blk = blockIdx.x;
  const int bn  = blk / 56;           // b*8 + n
  const int rem = blk % 56;
  const int h0  = (rem >> 2) * 4;
  const int w0  = (rem & 3) * 16;
  const int n   = bn & 7;

  __shared__ float bias_s[169];
  const int tid = threadIdx.x;
  if (tid < 169) bias_s[tid] = relbias[tid * NH + n];
  __syncthreads();

  const int p  = tid >> 2, dp = tid & 3;
  const int h  = h0 + (p >> 4);
  const int wr = w0 + (p & 15);
  const bool valid = (wr < WIMG);
  const int w  = valid ? wr : (WIMG - 1);
  const int hw = h * WIMG + w;

  int ph = h - 3; ph = ph < 0 ? 0 : (ph > 49 ? 49 : ph);
  int pw = w - 3; pw = pw < 0 ? 0 : (pw > 49 ? 49 : pw);
  const int l = ph * 50 + pw;

  const int bih = (h < 3) ? h : ((h < 53) ? 3 : h - 49);
  const int biw = (w < 3) ? w : ((w < 53) ? 3 : w - 49);
  const int bbase = bih * 13 + biw;

  const float* qb = q + ((size_t)bn * HWT + hw) * 32 + dp * 8;
  const float4 q0 = *(const float4*)qb;
  const float4 q1 = *(const float4*)(qb + 4);

  const int* srcl = src + l * 49;
  const float* kbase = kt + (size_t)bn * HWT * 32 + dp * 8;
  const float* vbase = vt + (size_t)bn * HWT * 32 + dp * 8;

  float acc[8];
#pragma unroll
  for (int i = 0; i < 8; ++i) acc[i] = 0.f;

#pragma unroll 7
  for (int ki = 0; ki < 7; ++ki) {
#pragma unroll
    for (int kj = 0; kj < 7; ++kj) {
      const int kidx = ki * 7 + kj;
      const int s = srcl[kidx];
      const float* kp = kbase + (size_t)s * 32;
      const float4 k0 = *(const float4*)kp;
      const float4 k1 = *(const float4*)(kp + 4);
      float part = q0.x * k0.x + q0.y * k0.y + q0.z * k0.z + q0.w * k0.w +
                   q1.x * k1.x + q1.y * k1.y + q1.z * k1.z + q1.w * k1.w;
      part += __shfl_xor(part, 1);
      part += __shfl_xor(part, 2);
      const float a = part + bias_s[bbase + ki * 13 + kj];
      const float* vp = vbase + (size_t)s * 32;
      const float4 v0 = *(const float4*)vp;
      const float4 v1 = *(const float4*)(vp + 4);
      acc[0] += a * v0.x; acc[1] += a * v0.y;
      acc[2] += a * v0.z; acc[3] += a * v0.w;
      acc[4] += a * v1.x; acc[5] += a * v1.y;
      acc[6] += a * v1.z; acc[7] += a * v1.w;
    }
  }

  if (valid) {
    float* ob = att + (size_t)(bn * 32 + dp * 8) * HWT + hw;
#pragma unroll
    for (int j = 0; j < 8; ++j) ob[(size_t)j * HWT] = acc[j];
  }
}

// ---------------------------------------------------------------------------
extern "C" void kernel_launch(void* const* d_in, const int* in_sizes, int n_in,
                              void* d_out, int out_size, void* d_ws, size_t ws_size,
                              hipStream_t stream) {
  const float* x       = (const float*)d_in[0];
  const float* qkv_w   = (const float*)d_in[1];
  const float* qkv_b   = (const float*)d_in[2];
  const float* proj_w  = (const float*)d_in[3];
  const float* proj_b  = (const float*)d_in[4];
  const float* relbias = (const float*)d_in[5];
  float* out = (float*)d_out;

  float* wsf = (float*)d_ws;
  float* q   = wsf;
  float* kt  = wsf + (size_t)QKV_ELEMS;
  float* vt  = wsf + 2 * (size_t)QKV_ELEMS;
  float* att = wsf + 3 * (size_t)QKV_ELEMS;
  int*   src = (int*)(wsf + 4 * (size_t)QKV_ELEMS);

  hipLaunchKernelGGL(build_src_k, dim3((2500 * 49 + 255) / 256), dim3(256), 0,
                     stream, src);
  hipLaunchKernelGGL((gemm_k<0>), dim3(25, 6, 2), dim3(256), 0, stream,
                     qkv_w, qkv_b, x, q);
  hipLaunchKernelGGL(attn_k, dim3(896), dim3(256), 0, stream,
                     q, kt, vt, src, relbias, att);
  hipLaunchKernelGGL((gemm_k<1>), dim3(25, 2, 2), dim3(256), 0, stream,
                     proj_w, proj_b, att, out);
}

// Round 2
// 92.912 us; speedup vs baseline: 1.7572x; 1.7572x over previous
//
#include <hip/hip_runtime.h>
#include <cstddef>
#include <cstdint>

#define HWT   3136        // 56*56
#define WIMG  56
#define CCH   256
#define NH    8
#define QKV_ELEMS (16 * HWT * 32)   // per-tensor q/k/v elements
#define SCALE 0.17677669529663687f  // 32^-0.5

typedef __attribute__((ext_vector_type(8))) short short8;
typedef __attribute__((ext_vector_type(4))) float f32x4;

__device__ __forceinline__ ushort f2bf(float f) {
  union { float f; uint32_t u; } v; v.f = f;
  uint32_t u = v.u;
  u += 0x7fffu + ((u >> 16) & 1u);   // round-to-nearest-even
  return (ushort)(u >> 16);
}

// ---------------------------------------------------------------------------
// Kernel 0: scrambled-gather source table (reshape-reinterpret semantics).
// ---------------------------------------------------------------------------
__global__ __launch_bounds__(256) void build_src_k(int* __restrict__ src) {
  int e = blockIdx.x * 256 + threadIdx.x;
  if (e >= 2500 * 49) return;
  int s = e / 2500;
  int pos = e % 2500;
  int i = pos / 50 + s / 7;
  int j = pos % 50 + s % 7;
  src[e] = i * WIMG + j;
}

// ---------------------------------------------------------------------------
// Convert both weight matrices to bf16 (row-major, k-contiguous already).
// ---------------------------------------------------------------------------
__global__ __launch_bounds__(256) void convw_k(
    const float* __restrict__ qkv_w, const float* __restrict__ proj_w,
    ushort* __restrict__ wq, ushort* __restrict__ wp) {
  int e = blockIdx.x * 256 + threadIdx.x;
  if (e < 768 * 256) wq[e] = f2bf(qkv_w[e]);
  else               wp[e - 768 * 256] = f2bf(proj_w[e - 768 * 256]);
}

// ---------------------------------------------------------------------------
// x (b, c, hw) f32  ->  xt (b, hw, c) bf16   (32x32 LDS tile transpose)
// ---------------------------------------------------------------------------
__global__ __launch_bounds__(256) void transpose_x_k(
    const float* __restrict__ x, ushort* __restrict__ xt) {
  __shared__ float tile[32][33];
  const int hw0 = blockIdx.x * 32, c0 = blockIdx.y * 32, b = blockIdx.z;
  const int tx = threadIdx.x & 31, ty = threadIdx.x >> 5;
  const float* xb = x + ((size_t)b * CCH + c0) * HWT + hw0;
#pragma unroll
  for (int i = 0; i < 4; ++i) {
    int c = ty + i * 8;
    tile[c][tx] = xb[(size_t)c * HWT + tx];
  }
  __syncthreads();
  ushort* xo = xt + ((size_t)b * HWT + hw0) * CCH + c0;
#pragma unroll
  for (int i = 0; i < 4; ++i) {
    int hwl = ty + i * 8;
    xo[(size_t)hwl * CCH + tx] = f2bf(tile[tx][hwl]);
  }
}

// ---------------------------------------------------------------------------
// bf16 MFMA GEMM, 128x128 tile, BK=32, 4 waves (2x2), 16x16x32 fragments.
// Both operands stored row-major with K contiguous ("B^T" form):
//   A rows = M dim, B rows = N dim. D[m][n] = sum_k A[m][k]*B[n][k]^T.
// LDS staged via global_load_lds (16B) with pre-swizzled global source:
//   chunk' = chunk ^ ((row>>1)&3)  -> 2-way bank aliasing on ds_read (free).
// MODE 0 (qkv): m=hw, n=o. Epilogue scatters q(*scale)/k/v fp32 (bn,hw,d).
// MODE 1 (proj): m=o, n=hw. Epilogue writes out (b,o,hw) + bias.
// ---------------------------------------------------------------------------
template <int MODE>
__global__ __launch_bounds__(256) void mfma_gemm_k(
    const ushort* __restrict__ A, int rowsA,
    const ushort* __restrict__ B, int rowsB,
    const float* __restrict__ biasv, float* __restrict__ outp) {
  __shared__ ushort Alds[128 * 32];
  __shared__ ushort Blds[128 * 32];

  const int t  = threadIdx.x;
  const int m0 = blockIdx.y * 128;
  const int n0 = blockIdx.x * 128;
  const int b  = blockIdx.z;

  const ushort* Ab = A + (MODE == 0 ? (size_t)b * HWT * CCH : 0);
  const ushort* Bb = B + (MODE == 1 ? (size_t)b * HWT * CCH : 0);

  const int lane  = t & 63;
  const int wid   = t >> 6;
  const int wm    = (wid >> 1) * 64;
  const int wn    = (wid & 1) * 64;
  const int lrow  = lane & 15;
  const int cwant = lane >> 4;
  const int csw   = (cwant ^ ((lrow >> 1) & 3)) * 8;  // swizzled elem offset

  const int srow   = t >> 2;   // staging row within 64-row half
  const int scslot = t & 3;
  const int wlds   = wid << 9; // wave's LDS base (elements): wid*1024B

  f32x4 acc[4][4];
#pragma unroll
  for (int i = 0; i < 4; ++i)
#pragma unroll
    for (int j = 0; j < 4; ++j) acc[i][j] = (f32x4){0.f, 0.f, 0.f, 0.f};

  for (int k0 = 0; k0 < CCH; k0 += 32) {
    __syncthreads();
#pragma unroll
    for (int h = 0; h < 2; ++h) {
      const int lr   = srow + h * 64;                    // LDS row 0..127
      const int csrc = (scslot ^ ((lr >> 1) & 3)) * 8;   // pre-swizzled src
      int ga = m0 + lr; ga = ga < rowsA ? ga : rowsA - 1;
      int gb = n0 + lr; gb = gb < rowsB ? gb : rowsB - 1;
      const ushort* gpa = Ab + (size_t)ga * CCH + k0 + csrc;
      const ushort* gpb = Bb + (size_t)gb * CCH + k0 + csrc;
      ushort* lpa = Alds + h * 2048 + wlds;
      ushort* lpb = Blds + h * 2048 + wlds;
      __builtin_amdgcn_global_load_lds(
          (const __attribute__((address_space(1))) void*)gpa,
          (__attribute__((address_space(3))) void*)lpa, 16, 0, 0);
      __builtin_amdgcn_global_load_lds(
          (const __attribute__((address_space(1))) void*)gpb,
          (__attribute__((address_space(3))) void*)lpb, 16, 0, 0);
    }
    __syncthreads();

    short8 af[4], bf[4];
#pragma unroll
    for (int mi = 0; mi < 4; ++mi)
      af[mi] = *(const short8*)&Alds[(wm + mi * 16 + lrow) * 32 + csw];
#pragma unroll
    for (int ni = 0; ni < 4; ++ni)
      bf[ni] = *(const short8*)&Blds[(wn + ni * 16 + lrow) * 32 + csw];
#pragma unroll
    for (int mi = 0; mi < 4; ++mi)
#pragma unroll
      for (int ni = 0; ni < 4; ++ni)
        acc[mi][ni] = __builtin_amdgcn_mfma_f32_16x16x32_bf16(
            af[mi], bf[ni], acc[mi][ni], 0, 0, 0);
  }

  const int row4 = (lane >> 4) * 4;  // D row base: row = row4 + reg
  if (MODE == 0) {
#pragma unroll
    for (int ni = 0; ni < 4; ++ni) {
      const int o = n0 + wn + ni * 16 + lrow;
      const int t3 = o >> 8, c = o & 255;
      const int head = c >> 5, d = c & 31;
      const float bv = biasv[o];
      const float sc = (t3 == 0) ? SCALE : 1.f;
      float* dst = outp + (size_t)t3 * QKV_ELEMS +
                   (size_t)(b * NH + head) * HWT * 32 + d;
#pragma unroll
      for (int mi = 0; mi < 4; ++mi)
#pragma unroll
        for (int r = 0; r < 4; ++r) {
          const int hw = m0 + wm + mi * 16 + row4 + r;
          if (hw < HWT) dst[(size_t)hw * 32] = (acc[mi][ni][r] + bv) * sc;
        }
    }
  } else {
#pragma unroll
    for (int mi = 0; mi < 4; ++mi)
#pragma unroll
      for (int r = 0; r < 4; ++r) {
        const int o = m0 + wm + mi * 16 + row4 + r;
        const float bv = biasv[o];
#pragma unroll
        for (int ni = 0; ni < 4; ++ni) {
          const int hw = n0 + wn + ni * 16 + lrow;
          if (hw < HWT)
            outp[((size_t)b * CCH + o) * HWT + hw] = acc[mi][ni][r] + bv;
        }
      }
  }
}

// ---------------------------------------------------------------------------
// Attention (no softmax): 4 threads/pixel, fp32 in, bf16 transposed out.
// att_t layout: (b, hw, c) bf16 -> k-contiguous B operand for proj GEMM.
// ---------------------------------------------------------------------------
__global__ __launch_bounds__(256) void attn_k(
    const float* __restrict__ q, const float* __restrict__ kt,
    const float* __restrict__ vt, const int* __restrict__ src,
    const float* __restrict__ relbias, ushort* __restrict__ att_t) {
  const int blk = blockIdx.x;
  const int bn  = blk / 56;           // b*8 + n
  const int rem = blk % 56;
  const int h0  = (rem >> 2) * 4;
  const int w0  = (rem & 3) * 16;
  const int n   = bn & 7;
  const int bb  = bn >> 3;

  __shared__ float bias_s[169];
  const int tid = threadIdx.x;
  if (tid < 169) bias_s[tid] = relbias[tid * NH + n];
  __syncthreads();

  const int p  = tid >> 2, dp = tid & 3;
  const int h  = h0 + (p >> 4);
  const int wr = w0 + (p & 15);
  const bool valid = (wr < WIMG);
  const int w  = valid ? wr : (WIMG - 1);
  const int hw = h * WIMG + w;

  int ph = h - 3; ph = ph < 0 ? 0 : (ph > 49 ? 49 : ph);
  int pw = w - 3; pw = pw < 0 ? 0 : (pw > 49 ? 49 : pw);
  const int l = ph * 50 + pw;

  const int bih = (h < 3) ? h : ((h < 53) ? 3 : h - 49);
  const int biw = (w < 3) ? w : ((w < 53) ? 3 : w - 49);
  const int bbase = bih * 13 + biw;

  const float* qb = q + ((size_t)bn * HWT + hw) * 32 + dp * 8;
  const float4 q0 = *(const float4*)qb;
  const float4 q1 = *(const float4*)(qb + 4);

  const int* srcl = src + l * 49;
  const float* kbase = kt + (size_t)bn * HWT * 32 + dp * 8;
  const float* vbase = vt + (size_t)bn * HWT * 32 + dp * 8;

  float acc[8];
#pragma unroll
  for (int i = 0; i < 8; ++i) acc[i] = 0.f;

#pragma unroll 7
  for (int ki = 0; ki < 7; ++ki) {
#pragma unroll
    for (int kj = 0; kj < 7; ++kj) {
      const int kidx = ki * 7 + kj;
      const int s = srcl[kidx];
      const float* kp = kbase + (size_t)s * 32;
      const float4 k0 = *(const float4*)kp;
      const float4 k1 = *(const float4*)(kp + 4);
      float part = q0.x * k0.x + q0.y * k0.y + q0.z * k0.z + q0.w * k0.w +
                   q1.x * k1.x + q1.y * k1.y + q1.z * k1.z + q1.w * k1.w;
      part += __shfl_xor(part, 1);
      part += __shfl_xor(part, 2);
      const float a = part + bias_s[bbase + ki * 13 + kj];
      const float* vp = vbase + (size_t)s * 32;
      const float4 v0 = *(const float4*)vp;
      const float4 v1 = *(const float4*)(vp + 4);
      acc[0] += a * v0.x; acc[1] += a * v0.y;
      acc[2] += a * v0.z; acc[3] += a * v0.w;
      acc[4] += a * v1.x; acc[5] += a * v1.y;
      acc[6] += a * v1.z; acc[7] += a * v1.w;
    }
  }

  if (valid) {
    ushort tmp[8];
#pragma unroll
    for (int j = 0; j < 8; ++j) tmp[j] = f2bf(acc[j]);
    ushort* ob = att_t + ((size_t)bb * HWT + hw) * CCH + n * 32 + dp * 8;
    *(short8*)ob = *(const short8*)tmp;
  }
}

// ---------------------------------------------------------------------------
extern "C" void kernel_launch(void* const* d_in, const int* in_sizes, int n_in,
                              void* d_out, int out_size, void* d_ws, size_t ws_size,
                              hipStream_t stream) {
  const float* x       = (const float*)d_in[0];
  const float* qkv_w   = (const float*)d_in[1];
  const float* qkv_b   = (const float*)d_in[2];
  const float* proj_w  = (const float*)d_in[3];
  const float* proj_b  = (const float*)d_in[4];
  const float* relbias = (const float*)d_in[5];
  float* out = (float*)d_out;

  float* wsf = (float*)d_ws;
  float*  q     = wsf;                                   // fp32, QKV_ELEMS
  float*  kt    = wsf + (size_t)QKV_ELEMS;
  float*  vt    = wsf + 2 * (size_t)QKV_ELEMS;
  ushort* xt    = (ushort*)(wsf + 3 * (size_t)QKV_ELEMS); // bf16 (b,hw,c)
  ushort* att_t = xt + (size_t)QKV_ELEMS;                 // bf16 (b,hw,c)
  ushort* wq    = att_t + (size_t)QKV_ELEMS;              // bf16 768x256
  ushort* wp    = wq + 768 * 256;                         // bf16 256x256
  int*    src   = (int*)(wp + 256 * 256);

  hipLaunchKernelGGL(build_src_k, dim3(479), dim3(256), 0, stream, src);
  hipLaunchKernelGGL(convw_k, dim3(1024), dim3(256), 0, stream,
                     qkv_w, proj_w, wq, wp);
  hipLaunchKernelGGL(transpose_x_k, dim3(98, 8, 2), dim3(256), 0, stream,
                     x, xt);
  // qkv: A=xt (m=hw, 3136 rows), B=wq (n=o, 768 rows)
  hipLaunchKernelGGL((mfma_gemm_k<0>), dim3(6, 25, 2), dim3(256), 0, stream,
                     xt, HWT, wq, 768, qkv_b, q);
  hipLaunchKernelGGL(attn_k, dim3(896), dim3(256), 0, stream,
                     q, kt, vt, src, relbias, att_t);
  // proj: A=wp (m=o, 256 rows), B=att_t (n=hw, 3136 rows)
  hipLaunchKernelGGL((mfma_gemm_k<1>), dim3(25, 2, 2), dim3(256), 0, stream,
                     wp, 256, att_t, HWT, proj_b, out);
}

// Round 3
// 79.986 us; speedup vs baseline: 2.0412x; 1.1616x over previous
//
#include <hip/hip_runtime.h>
#include <cstddef>
#include <cstdint>

#define HWT   3136        // 56*56
#define WIMG  56
#define CCH   256
#define NH    8
#define QKV_ELEMS (16 * HWT * 32)   // per-tensor q/k/v elements
#define SCALE 0.17677669529663687f  // 32^-0.5

typedef __attribute__((ext_vector_type(8))) short short8;
typedef __attribute__((ext_vector_type(4))) float f32x4;
typedef _Float16 half2v __attribute__((ext_vector_type(2)));
typedef _Float16 half4v __attribute__((ext_vector_type(4)));
typedef _Float16 half8v __attribute__((ext_vector_type(8)));

#if defined(__has_builtin)
#if __has_builtin(__builtin_amdgcn_fdot2)
#define HAVE_FDOT2 1
#endif
#endif
#ifndef HAVE_FDOT2
#define HAVE_FDOT2 0
#endif

__device__ __forceinline__ ushort f2bf(float f) {
  union { float f; uint32_t u; } v; v.f = f;
  uint32_t u = v.u;
  u += 0x7fffu + ((u >> 16) & 1u);   // round-to-nearest-even
  return (ushort)(u >> 16);
}

// ---------------------------------------------------------------------------
// Kernel 0: scrambled-gather source table (reshape-reinterpret semantics).
// f = l*49 + k; s = f/2500; pos = f%2500; src pixel = (pos/50+s/7, pos%50+s%7)
// ---------------------------------------------------------------------------
__global__ __launch_bounds__(256) void build_src_k(int* __restrict__ src) {
  int e = blockIdx.x * 256 + threadIdx.x;
  if (e >= 2500 * 49) return;
  int s = e / 2500;
  int pos = e % 2500;
  int i = pos / 50 + s / 7;
  int j = pos % 50 + s % 7;
  src[e] = i * WIMG + j;
}

// ---------------------------------------------------------------------------
// Convert both weight matrices to bf16 (row-major, k-contiguous already).
// ---------------------------------------------------------------------------
__global__ __launch_bounds__(256) void convw_k(
    const float* __restrict__ qkv_w, const float* __restrict__ proj_w,
    ushort* __restrict__ wq, ushort* __restrict__ wp) {
  int e = blockIdx.x * 256 + threadIdx.x;
  if (e < 768 * 256) wq[e] = f2bf(qkv_w[e]);
  else               wp[e - 768 * 256] = f2bf(proj_w[e - 768 * 256]);
}

// ---------------------------------------------------------------------------
// x (b, c, hw) f32  ->  xt (b, hw, c) bf16   (32x32 LDS tile transpose)
// ---------------------------------------------------------------------------
__global__ __launch_bounds__(256) void transpose_x_k(
    const float* __restrict__ x, ushort* __restrict__ xt) {
  __shared__ float tile[32][33];
  const int hw0 = blockIdx.x * 32, c0 = blockIdx.y * 32, b = blockIdx.z;
  const int tx = threadIdx.x & 31, ty = threadIdx.x >> 5;
  const float* xb = x + ((size_t)b * CCH + c0) * HWT + hw0;
#pragma unroll
  for (int i = 0; i < 4; ++i) {
    int c = ty + i * 8;
    tile[c][tx] = xb[(size_t)c * HWT + tx];
  }
  __syncthreads();
  ushort* xo = xt + ((size_t)b * HWT + hw0) * CCH + c0;
#pragma unroll
  for (int i = 0; i < 4; ++i) {
    int hwl = ty + i * 8;
    xo[(size_t)hwl * CCH + tx] = f2bf(tile[tx][hwl]);
  }
}

// ---------------------------------------------------------------------------
// bf16 MFMA GEMM, 128x128 tile, BK=32, 4 waves (2x2), 16x16x32 fragments.
// A rows = M dim, B rows = N dim, both k-contiguous. B is the per-batch
// activation in both modes.
// MODE 0 (qkv): m=o (wq), n=hw (xt). Epilogue: fp16 q(*scale)/k/v (bn,hw,d),
//   lane r-quad = 4 consecutive d -> packed 8B stores.
// MODE 1 (proj): m=o (wp), n=hw (att_t). Epilogue: fp32 out (b,o,hw) + bias.
// ---------------------------------------------------------------------------
template <int MODE>
__global__ __launch_bounds__(256) void mfma_gemm_k(
    const ushort* __restrict__ A, int rowsA,
    const ushort* __restrict__ B, int rowsB,
    const float* __restrict__ biasv, void* __restrict__ outp) {
  __shared__ ushort Alds[128 * 32];
  __shared__ ushort Blds[128 * 32];

  const int t  = threadIdx.x;
  const int m0 = blockIdx.y * 128;
  const int n0 = blockIdx.x * 128;
  const int b  = blockIdx.z;

  const ushort* Ab = A;
  const ushort* Bb = B + (size_t)b * HWT * CCH;

  const int lane  = t & 63;
  const int wid   = t >> 6;
  const int wm    = (wid >> 1) * 64;
  const int wn    = (wid & 1) * 64;
  const int lrow  = lane & 15;
  const int cwant = lane >> 4;
  const int csw   = (cwant ^ ((lrow >> 1) & 3)) * 8;  // swizzled elem offset

  const int srow   = t >> 2;   // staging row within 64-row half
  const int scslot = t & 3;
  const int wlds   = wid << 9; // wave's LDS base (elements)

  f32x4 acc[4][4];
#pragma unroll
  for (int i = 0; i < 4; ++i)
#pragma unroll
    for (int j = 0; j < 4; ++j) acc[i][j] = (f32x4){0.f, 0.f, 0.f, 0.f};

  for (int k0 = 0; k0 < CCH; k0 += 32) {
    __syncthreads();
#pragma unroll
    for (int h = 0; h < 2; ++h) {
      const int lr   = srow + h * 64;
      const int csrc = (scslot ^ ((lr >> 1) & 3)) * 8;
      int ga = m0 + lr; ga = ga < rowsA ? ga : rowsA - 1;
      int gb = n0 + lr; gb = gb < rowsB ? gb : rowsB - 1;
      const ushort* gpa = Ab + (size_t)ga * CCH + k0 + csrc;
      const ushort* gpb = Bb + (size_t)gb * CCH + k0 + csrc;
      ushort* lpa = Alds + h * 2048 + wlds;
      ushort* lpb = Blds + h * 2048 + wlds;
      __builtin_amdgcn_global_load_lds(
          (const __attribute__((address_space(1))) void*)gpa,
          (__attribute__((address_space(3))) void*)lpa, 16, 0, 0);
      __builtin_amdgcn_global_load_lds(
          (const __attribute__((address_space(1))) void*)gpb,
          (__attribute__((address_space(3))) void*)lpb, 16, 0, 0);
    }
    __syncthreads();

    short8 af[4], bf[4];
#pragma unroll
    for (int mi = 0; mi < 4; ++mi)
      af[mi] = *(const short8*)&Alds[(wm + mi * 16 + lrow) * 32 + csw];
#pragma unroll
    for (int ni = 0; ni < 4; ++ni)
      bf[ni] = *(const short8*)&Blds[(wn + ni * 16 + lrow) * 32 + csw];
#pragma unroll
    for (int mi = 0; mi < 4; ++mi)
#pragma unroll
      for (int ni = 0; ni < 4; ++ni)
        acc[mi][ni] = __builtin_amdgcn_mfma_f32_16x16x32_bf16(
            af[mi], bf[ni], acc[mi][ni], 0, 0, 0);
  }

  const int row4 = (lane >> 4) * 4;  // D row base: row = row4 + reg
  if (MODE == 0) {
    _Float16* qh = (_Float16*)outp;
#pragma unroll
    for (int mi = 0; mi < 4; ++mi) {
      const int o0 = m0 + wm + mi * 16 + row4;   // quad of consecutive o
      const int t3 = o0 >> 8, c0 = o0 & 255;
      const int head = c0 >> 5, d0 = c0 & 31;
      const float sc = (t3 == 0) ? SCALE : 1.f;
      float bv[4];
#pragma unroll
      for (int r = 0; r < 4; ++r) bv[r] = biasv[o0 + r];
      _Float16* base = qh + (size_t)t3 * QKV_ELEMS +
                       (size_t)(b * NH + head) * HWT * 32 + d0;
#pragma unroll
      for (int ni = 0; ni < 4; ++ni) {
        const int hw = n0 + wn + ni * 16 + lrow;
        if (hw < HWT) {
          half4v pack;
#pragma unroll
          for (int r = 0; r < 4; ++r)
            pack[r] = (_Float16)((acc[mi][ni][r] + bv[r]) * sc);
          *(half4v*)(base + (size_t)hw * 32) = pack;
        }
      }
    }
  } else {
    float* op = (float*)outp;
#pragma unroll
    for (int mi = 0; mi < 4; ++mi)
#pragma unroll
      for (int r = 0; r < 4; ++r) {
        const int o = m0 + wm + mi * 16 + row4 + r;
        const float bvv = biasv[o];
#pragma unroll
        for (int ni = 0; ni < 4; ++ni) {
          const int hw = n0 + wn + ni * 16 + lrow;
          if (hw < HWT)
            op[((size_t)b * CCH + o) * HWT + hw] = acc[mi][ni][r] + bvv;
        }
      }
  }
}

// ---------------------------------------------------------------------------
// QK: one wave per pixel, lane = neighbor j (49 of 64 active).
// attnW[(bn*HWT+pixel)*49 + j] = (src_u16 << 16) | f16bits(q.k + bias)
// ---------------------------------------------------------------------------
__global__ __launch_bounds__(256) void attn_qk_k(
    const _Float16* __restrict__ q_h, const _Float16* __restrict__ k_h,
    const int* __restrict__ src, const float* __restrict__ relbias,
    uint32_t* __restrict__ attnW) {
  const int bn = blockIdx.y;
  const int n  = bn & 7;

  __shared__ float bias_s[169];
  const int tid = threadIdx.x;
  if (tid < 169) bias_s[tid] = relbias[tid * NH + n];
  __syncthreads();

  const int wid = tid >> 6, j = tid & 63;
  const int pixel = blockIdx.x * 4 + wid;
  const int h = pixel / 56, w = pixel % 56;

  int ph = h - 3; ph = ph < 0 ? 0 : (ph > 49 ? 49 : ph);
  int pw = w - 3; pw = pw < 0 ? 0 : (pw > 49 ? 49 : pw);
  const int l = ph * 50 + pw;

  const int bih = (h < 3) ? h : ((h < 53) ? 3 : h - 49);
  const int biw = (w < 3) ? w : ((w < 53) ? 3 : w - 49);
  const int bbase = bih * 13 + biw;

  union V64 { uint4 u[4]; half2v h[16]; };
  V64 Q;
  const uint4* qp = (const uint4*)(q_h + ((size_t)bn * HWT + pixel) * 32);
#pragma unroll
  for (int i = 0; i < 4; ++i) Q.u[i] = qp[i];

  if (j >= 49) return;

  const int s = src[l * 49 + j];
  V64 K;
  const uint4* kp = (const uint4*)(k_h + ((size_t)bn * HWT + s) * 32);
#pragma unroll
  for (int i = 0; i < 4; ++i) K.u[i] = kp[i];

  float a0 = 0.f, a1 = 0.f, a2 = 0.f, a3 = 0.f;
#if HAVE_FDOT2
#pragma unroll
  for (int i = 0; i < 16; i += 4) {
    a0 = __builtin_amdgcn_fdot2(K.h[i + 0], Q.h[i + 0], a0, false);
    a1 = __builtin_amdgcn_fdot2(K.h[i + 1], Q.h[i + 1], a1, false);
    a2 = __builtin_amdgcn_fdot2(K.h[i + 2], Q.h[i + 2], a2, false);
    a3 = __builtin_amdgcn_fdot2(K.h[i + 3], Q.h[i + 3], a3, false);
  }
#else
#pragma unroll
  for (int i = 0; i < 16; i += 4) {
    a0 += (float)K.h[i+0][0]*(float)Q.h[i+0][0] + (float)K.h[i+0][1]*(float)Q.h[i+0][1];
    a1 += (float)K.h[i+1][0]*(float)Q.h[i+1][0] + (float)K.h[i+1][1]*(float)Q.h[i+1][1];
    a2 += (float)K.h[i+2][0]*(float)Q.h[i+2][0] + (float)K.h[i+2][1]*(float)Q.h[i+2][1];
    a3 += (float)K.h[i+3][0]*(float)Q.h[i+3][0] + (float)K.h[i+3][1]*(float)Q.h[i+3][1];
  }
#endif
  float a = (a0 + a1) + (a2 + a3);
  a += bias_s[bbase + (j / 7) * 13 + (j % 7)];

  union { _Float16 hh; uint16_t us; } cv;
  cv.hh = (_Float16)a;
  attnW[((size_t)bn * HWT + pixel) * 49 + j] = ((uint32_t)s << 16) | cv.us;
}

// ---------------------------------------------------------------------------
// PV: block = 64 pixels; attn+src tile in LDS; thread = (pixel, d-octet).
// out att_t (b, hw, c) bf16 for the proj GEMM.
// ---------------------------------------------------------------------------
__global__ __launch_bounds__(256) void attn_pv_k(
    const uint32_t* __restrict__ attnW, const _Float16* __restrict__ v_h,
    ushort* __restrict__ att_t) {
  const int bn = blockIdx.y;
  const int b = bn >> 3, n = bn & 7;
  const int px0 = blockIdx.x * 64;

  __shared__ uint32_t attn_s[64 * 49];
  const int tid = threadIdx.x;
  const uint32_t* gsrc = attnW + ((size_t)bn * HWT + px0) * 49;
  for (int i = tid; i < 64 * 49; i += 256) attn_s[i] = gsrc[i];
  __syncthreads();

  const int px = tid >> 2, dq = tid & 3;
  const int hw = px0 + px;
  const _Float16* vb = v_h + (size_t)bn * HWT * 32 + dq * 8;

  float acc[8];
#pragma unroll
  for (int d = 0; d < 8; ++d) acc[d] = 0.f;

#pragma unroll 7
  for (int j = 0; j < 49; ++j) {
    const uint32_t u = attn_s[px * 49 + j];
    union { uint16_t us; _Float16 hh; } cv;
    cv.us = (uint16_t)(u & 0xffffu);
    const float a = (float)cv.hh;
    const int s = (int)(u >> 16);
    const half8v v = *(const half8v*)(vb + (size_t)s * 32);
#pragma unroll
    for (int d = 0; d < 8; ++d) acc[d] += a * (float)v[d];
  }

  ushort tmp[8];
#pragma unroll
  for (int d = 0; d < 8; ++d) tmp[d] = f2bf(acc[d]);
  *(short8*)(att_t + ((size_t)b * HWT + hw) * CCH + n * 32 + dq * 8) =
      *(const short8*)tmp;
}

// ---------------------------------------------------------------------------
extern "C" void kernel_launch(void* const* d_in, const int* in_sizes, int n_in,
                              void* d_out, int out_size, void* d_ws, size_t ws_size,
                              hipStream_t stream) {
  const float* x       = (const float*)d_in[0];
  const float* qkv_w   = (const float*)d_in[1];
  const float* qkv_b   = (const float*)d_in[2];
  const float* proj_w  = (const float*)d_in[3];
  const float* proj_b  = (const float*)d_in[4];
  const float* relbias = (const float*)d_in[5];
  float* out = (float*)d_out;

  char* wsb = (char*)d_ws;
  _Float16* qh    = (_Float16*)wsb;                    // q,k,v fp16, 3*QKV_ELEMS
  uint32_t* attnW = (uint32_t*)(wsb + (size_t)3 * QKV_ELEMS * 2);
  ushort*   xt    = (ushort*)((char*)attnW + (size_t)16 * HWT * 49 * 4);
  ushort*   wq    = xt + (size_t)QKV_ELEMS;            // bf16 768x256
  ushort*   wp    = wq + 768 * 256;                    // bf16 256x256
  int*      src   = (int*)(wp + 256 * 256);
  ushort*   att_t = xt;  // alias: xt last read by qkv GEMM, before PV writes

  _Float16* kh = qh + (size_t)QKV_ELEMS;
  _Float16* vh = qh + (size_t)2 * QKV_ELEMS;

  hipLaunchKernelGGL(build_src_k, dim3(479), dim3(256), 0, stream, src);
  hipLaunchKernelGGL(convw_k, dim3(1024), dim3(256), 0, stream,
                     qkv_w, proj_w, wq, wp);
  hipLaunchKernelGGL(transpose_x_k, dim3(98, 8, 2), dim3(256), 0, stream,
                     x, xt);
  // qkv: A=wq (m=o, 768 rows), B=xt (n=hw) -> fp16 q/k/v
  hipLaunchKernelGGL((mfma_gemm_k<0>), dim3(25, 6, 2), dim3(256), 0, stream,
                     wq, 768, xt, HWT, qkv_b, (void*)qh);
  hipLaunchKernelGGL(attn_qk_k, dim3(784, 16), dim3(256), 0, stream,
                     qh, kh, src, relbias, attnW);
  hipLaunchKernelGGL(attn_pv_k, dim3(49, 16), dim3(256), 0, stream,
                     attnW, vh, att_t);
  // proj: A=wp (m=o, 256 rows), B=att_t (n=hw) -> fp32 out
  hipLaunchKernelGGL((mfma_gemm_k<1>), dim3(25, 2, 2), dim3(256), 0, stream,
                     wp, 256, att_t, HWT, proj_b, (void*)out);
}

// Round 4
// 66.997 us; speedup vs baseline: 2.4369x; 1.1939x over previous
//
#include <hip/hip_runtime.h>
#include <cstddef>
#include <cstdint>

#define HWT   3136        // 56*56
#define WIMG  56
#define CCH   256
#define NH    8
#define QKV_ELEMS (16 * HWT * 32)   // per-tensor q/k/v elements
#define SCALE 0.17677669529663687f  // 32^-0.5

typedef __attribute__((ext_vector_type(8))) short short8;
typedef __attribute__((ext_vector_type(4))) short short4v;
typedef __attribute__((ext_vector_type(4))) float f32x4;
typedef _Float16 half2v __attribute__((ext_vector_type(2)));
typedef _Float16 half4v __attribute__((ext_vector_type(4)));

#if defined(__has_builtin)
#if __has_builtin(__builtin_amdgcn_fdot2)
#define HAVE_FDOT2 1
#endif
#endif
#ifndef HAVE_FDOT2
#define HAVE_FDOT2 0
#endif

__device__ __forceinline__ ushort f2bf(float f) {
  union { float f; uint32_t u; } v; v.f = f;
  uint32_t u = v.u;
  u += 0x7fffu + ((u >> 16) & 1u);   // round-to-nearest-even
  return (ushort)(u >> 16);
}

// ---------------------------------------------------------------------------
// prep: z<2 -> transpose x (b,c,hw) f32 -> xt (b,hw,c) bf16 (32x32 LDS tile)
//       z==2 -> convert qkv_w / proj_w to bf16 (2 elems/thread)
// ---------------------------------------------------------------------------
__global__ __launch_bounds__(256) void prep_k(
    const float* __restrict__ x, const float* __restrict__ qkv_w,
    const float* __restrict__ proj_w, ushort* __restrict__ xt,
    ushort* __restrict__ wq, ushort* __restrict__ wp) {
  if (blockIdx.z == 2) {
    int base = ((blockIdx.y * 98 + blockIdx.x) * 256 + threadIdx.x) * 2;
#pragma unroll
    for (int e = base; e < base + 2; ++e) {
      if (e < 768 * 256) wq[e] = f2bf(qkv_w[e]);
      else if (e < 768 * 256 + 256 * 256) {
        int e2 = e - 768 * 256;
        wp[e2] = f2bf(proj_w[e2]);
      }
    }
    return;
  }
  __shared__ float tile[32][33];
  const int hw0 = blockIdx.x * 32, c0 = blockIdx.y * 32, b = blockIdx.z;
  const int tx = threadIdx.x & 31, ty = threadIdx.x >> 5;
  const float* xb = x + ((size_t)b * CCH + c0) * HWT + hw0;
#pragma unroll
  for (int i = 0; i < 4; ++i) {
    int c = ty + i * 8;
    tile[c][tx] = xb[(size_t)c * HWT + tx];
  }
  __syncthreads();
  ushort* xo = xt + ((size_t)b * HWT + hw0) * CCH + c0;
#pragma unroll
  for (int i = 0; i < 4; ++i) {
    int hwl = ty + i * 8;
    xo[(size_t)hwl * CCH + tx] = f2bf(tile[tx][hwl]);
  }
}

// ---------------------------------------------------------------------------
// bf16 MFMA GEMM, 128x128 tile, BK=32, 4 waves (2x2), 16x16x32 fragments.
// A rows = M dim (weights), B rows = N dim (per-batch activation),
// both k-contiguous.
// MODE 0 (qkv): epilogue -> fp16 q(*scale)/k/v (bn,hw,d) packed 8B stores.
// MODE 1 (proj): epilogue -> fp32 out (b,o,hw) + bias.
// ---------------------------------------------------------------------------
template <int MODE>
__global__ __launch_bounds__(256) void mfma_gemm_k(
    const ushort* __restrict__ A, int rowsA,
    const ushort* __restrict__ B, int rowsB,
    const float* __restrict__ biasv, void* __restrict__ outp) {
  __shared__ ushort Alds[128 * 32];
  __shared__ ushort Blds[128 * 32];

  const int t  = threadIdx.x;
  const int m0 = blockIdx.y * 128;
  const int n0 = blockIdx.x * 128;
  const int b  = blockIdx.z;

  const ushort* Ab = A;
  const ushort* Bb = B + (size_t)b * HWT * CCH;

  const int lane  = t & 63;
  const int wid   = t >> 6;
  const int wm    = (wid >> 1) * 64;
  const int wn    = (wid & 1) * 64;
  const int lrow  = lane & 15;
  const int cwant = lane >> 4;
  const int csw   = (cwant ^ ((lrow >> 1) & 3)) * 8;

  const int srow   = t >> 2;
  const int scslot = t & 3;
  const int wlds   = wid << 9;

  f32x4 acc[4][4];
#pragma unroll
  for (int i = 0; i < 4; ++i)
#pragma unroll
    for (int j = 0; j < 4; ++j) acc[i][j] = (f32x4){0.f, 0.f, 0.f, 0.f};

  for (int k0 = 0; k0 < CCH; k0 += 32) {
    __syncthreads();
#pragma unroll
    for (int h = 0; h < 2; ++h) {
      const int lr   = srow + h * 64;
      const int csrc = (scslot ^ ((lr >> 1) & 3)) * 8;
      int ga = m0 + lr; ga = ga < rowsA ? ga : rowsA - 1;
      int gb = n0 + lr; gb = gb < rowsB ? gb : rowsB - 1;
      const ushort* gpa = Ab + (size_t)ga * CCH + k0 + csrc;
      const ushort* gpb = Bb + (size_t)gb * CCH + k0 + csrc;
      ushort* lpa = Alds + h * 2048 + wlds;
      ushort* lpb = Blds + h * 2048 + wlds;
      __builtin_amdgcn_global_load_lds(
          (const __attribute__((address_space(1))) void*)gpa,
          (__attribute__((address_space(3))) void*)lpa, 16, 0, 0);
      __builtin_amdgcn_global_load_lds(
          (const __attribute__((address_space(1))) void*)gpb,
          (__attribute__((address_space(3))) void*)lpb, 16, 0, 0);
    }
    __syncthreads();

    short8 af[4], bf[4];
#pragma unroll
    for (int mi = 0; mi < 4; ++mi)
      af[mi] = *(const short8*)&Alds[(wm + mi * 16 + lrow) * 32 + csw];
#pragma unroll
    for (int ni = 0; ni < 4; ++ni)
      bf[ni] = *(const short8*)&Blds[(wn + ni * 16 + lrow) * 32 + csw];
#pragma unroll
    for (int mi = 0; mi < 4; ++mi)
#pragma unroll
      for (int ni = 0; ni < 4; ++ni)
        acc[mi][ni] = __builtin_amdgcn_mfma_f32_16x16x32_bf16(
            af[mi], bf[ni], acc[mi][ni], 0, 0, 0);
  }

  const int row4 = (lane >> 4) * 4;
  if (MODE == 0) {
    _Float16* qh = (_Float16*)outp;
#pragma unroll
    for (int mi = 0; mi < 4; ++mi) {
      const int o0 = m0 + wm + mi * 16 + row4;
      const int t3 = o0 >> 8, c0 = o0 & 255;
      const int head = c0 >> 5, d0 = c0 & 31;
      const float sc = (t3 == 0) ? SCALE : 1.f;
      float bv[4];
#pragma unroll
      for (int r = 0; r < 4; ++r) bv[r] = biasv[o0 + r];
      _Float16* base = qh + (size_t)t3 * QKV_ELEMS +
                       (size_t)(b * NH + head) * HWT * 32 + d0;
#pragma unroll
      for (int ni = 0; ni < 4; ++ni) {
        const int hw = n0 + wn + ni * 16 + lrow;
        if (hw < HWT) {
          half4v pack;
#pragma unroll
          for (int r = 0; r < 4; ++r)
            pack[r] = (_Float16)((acc[mi][ni][r] + bv[r]) * sc);
          *(half4v*)(base + (size_t)hw * 32) = pack;
        }
      }
    }
  } else {
    float* op = (float*)outp;
#pragma unroll
    for (int mi = 0; mi < 4; ++mi)
#pragma unroll
      for (int r = 0; r < 4; ++r) {
        const int o = m0 + wm + mi * 16 + row4 + r;
        const float bvv = biasv[o];
#pragma unroll
        for (int ni = 0; ni < 4; ++ni) {
          const int hw = n0 + wn + ni * 16 + lrow;
          if (hw < HWT)
            op[((size_t)b * CCH + o) * HWT + hw] = acc[mi][ni][r] + bvv;
        }
      }
  }
}

// ---------------------------------------------------------------------------
// Fused attention: block = 32 pixels x one (b,n); 256 threads; grid 1568.
// Phase A: wave-per-pixel QK (lane = neighbor j, src computed inline from the
//          reshape-reinterpret arithmetic), attn -> LDS as (src<<16 | f16).
// Phase B: 8 threads/pixel PV (4 channels each), out att_t (b,hw,c) bf16.
// ---------------------------------------------------------------------------
__global__ __launch_bounds__(256) void attn_fused_k(
    const _Float16* __restrict__ q_h, const _Float16* __restrict__ k_h,
    const _Float16* __restrict__ v_h, const float* __restrict__ relbias,
    ushort* __restrict__ att_t) {
  // bijective XCD swizzle (1568 % 8 == 0): each XCD gets 2 bn values.
  const int id  = blockIdx.x;
  const int idx = (id & 7) * 196 + (id >> 3);
  const int bn  = idx / 98;
  const int px0 = (idx % 98) * 32;
  const int b = bn >> 3, n = bn & 7;

  __shared__ float bias_s[169];
  __shared__ uint32_t as_lds[32 * 49];

  const int tid = threadIdx.x;
  if (tid < 169) bias_s[tid] = relbias[tid * NH + n];
  __syncthreads();

  const int wid = tid >> 6, lane = tid & 63;
  const _Float16* kb = k_h + (size_t)bn * HWT * 32;

#pragma unroll 2
  for (int pass = 0; pass < 8; ++pass) {
    const int pxl = pass * 4 + wid;
    const int px = px0 + pxl;
    const int h = px / WIMG, w = px % WIMG;
    int ph = h - 3; ph = ph < 0 ? 0 : (ph > 49 ? 49 : ph);
    int pw = w - 3; pw = pw < 0 ? 0 : (pw > 49 ? 49 : pw);
    const int l = ph * 50 + pw;
    const int bih = (h < 3) ? h : ((h < 53) ? 3 : h - 49);
    const int biw = (w < 3) ? w : ((w < 53) ? 3 : w - 49);
    const int bbase = bih * 13 + biw;

    union V64 { uint4 u[4]; half2v hv[16]; };
    V64 Q;
    const uint4* qp = (const uint4*)(q_h + ((size_t)bn * HWT + px) * 32);
#pragma unroll
    for (int i = 0; i < 4; ++i) Q.u[i] = qp[i];

    if (lane < 49) {
      const int f = l * 49 + lane;
      const int sp = f / 2500;
      const int pos = f - sp * 2500;
      const int si = pos / 50;
      const int sj = pos - si * 50;
      const int s = (si + sp / 7) * WIMG + sj + sp % 7;

      V64 K;
      const uint4* kp = (const uint4*)(kb + (size_t)s * 32);
#pragma unroll
      for (int i = 0; i < 4; ++i) K.u[i] = kp[i];

      float a0 = 0.f, a1 = 0.f, a2 = 0.f, a3 = 0.f;
#if HAVE_FDOT2
#pragma unroll
      for (int i = 0; i < 16; i += 4) {
        a0 = __builtin_amdgcn_fdot2(K.hv[i + 0], Q.hv[i + 0], a0, false);
        a1 = __builtin_amdgcn_fdot2(K.hv[i + 1], Q.hv[i + 1], a1, false);
        a2 = __builtin_amdgcn_fdot2(K.hv[i + 2], Q.hv[i + 2], a2, false);
        a3 = __builtin_amdgcn_fdot2(K.hv[i + 3], Q.hv[i + 3], a3, false);
      }
#else
#pragma unroll
      for (int i = 0; i < 16; ++i) {
        a0 += (float)K.hv[i][0] * (float)Q.hv[i][0];
        a1 += (float)K.hv[i][1] * (float)Q.hv[i][1];
      }
#endif
      float a = (a0 + a1) + (a2 + a3);
      a += bias_s[bbase + (lane / 7) * 13 + lane % 7];

      union { _Float16 hh; uint16_t us; } cv;
      cv.hh = (_Float16)a;
      as_lds[pxl * 49 + lane] = ((uint32_t)s << 16) | cv.us;
    }
  }
  __syncthreads();

  // Phase B: thread = (pixel, 4-channel group)
  const int pxb = tid >> 3, oc = tid & 7;
  const _Float16* vb = v_h + (size_t)bn * HWT * 32 + oc * 4;
  const uint32_t* arow = &as_lds[pxb * 49];

  float acc[4] = {0.f, 0.f, 0.f, 0.f};
#pragma unroll 7
  for (int j = 0; j < 49; ++j) {
    const uint32_t u = arow[j];
    union { uint16_t us; _Float16 hh; } cv;
    cv.us = (uint16_t)(u & 0xffffu);
    const float a = (float)cv.hh;
    const int s = (int)(u >> 16);
    const half4v v = *(const half4v*)(vb + (size_t)s * 32);
#pragma unroll
    for (int d = 0; d < 4; ++d) acc[d] += a * (float)v[d];
  }

  ushort tmp[4];
#pragma unroll
  for (int d = 0; d < 4; ++d) tmp[d] = f2bf(acc[d]);
  *(short4v*)(att_t + ((size_t)b * HWT + px0 + pxb) * CCH + n * 32 + oc * 4) =
      *(const short4v*)tmp;
}

// ---------------------------------------------------------------------------
extern "C" void kernel_launch(void* const* d_in, const int* in_sizes, int n_in,
                              void* d_out, int out_size, void* d_ws, size_t ws_size,
                              hipStream_t stream) {
  const float* x       = (const float*)d_in[0];
  const float* qkv_w   = (const float*)d_in[1];
  const float* qkv_b   = (const float*)d_in[2];
  const float* proj_w  = (const float*)d_in[3];
  const float* proj_b  = (const float*)d_in[4];
  const float* relbias = (const float*)d_in[5];
  float* out = (float*)d_out;

  char* wsb = (char*)d_ws;
  _Float16* qh = (_Float16*)wsb;                       // q,k,v fp16
  _Float16* kh = qh + (size_t)QKV_ELEMS;
  _Float16* vh = qh + (size_t)2 * QKV_ELEMS;
  ushort*   xt = (ushort*)(wsb + (size_t)3 * QKV_ELEMS * 2); // bf16 (b,hw,c)
  ushort*   wq = xt + (size_t)QKV_ELEMS;               // bf16 768x256
  ushort*   wp = wq + 768 * 256;                       // bf16 256x256
  ushort*   att_t = xt;  // alias: xt fully consumed by qkv GEMM first

  hipLaunchKernelGGL(prep_k, dim3(98, 8, 3), dim3(256), 0, stream,
                     x, qkv_w, proj_w, xt, wq, wp);
  // qkv: A=wq (m=o, 768 rows), B=xt (n=hw) -> fp16 q/k/v
  hipLaunchKernelGGL((mfma_gemm_k<0>), dim3(25, 6, 2), dim3(256), 0, stream,
                     wq, 768, xt, HWT, qkv_b, (void*)qh);
  hipLaunchKernelGGL(attn_fused_k, dim3(1568), dim3(256), 0, stream,
                     qh, kh, vh, relbias, att_t);
  // proj: A=wp (m=o, 256 rows), B=att_t (n=hw) -> fp32 out
  hipLaunchKernelGGL((mfma_gemm_k<1>), dim3(25, 2, 2), dim3(256), 0, stream,
                     wp, 256, att_t, HWT, proj_b, (void*)out);
}

// Round 5
// 64.500 us; speedup vs baseline: 2.5312x; 1.0387x over previous
//
#include <hip/hip_runtime.h>
#include <cstddef>
#include <cstdint>

#define HWT   3136        // 56*56
#define WIMG  56
#define CCH   256
#define NH    8
#define QKV_ELEMS (16 * HWT * 32)   // per-tensor q/k/v elements
#define SCALE 0.17677669529663687f  // 32^-0.5

typedef __attribute__((ext_vector_type(8))) short short8;
typedef __attribute__((ext_vector_type(4))) short short4v;
typedef __attribute__((ext_vector_type(4))) float f32x4;
typedef _Float16 half2v __attribute__((ext_vector_type(2)));
typedef _Float16 half4v __attribute__((ext_vector_type(4)));

#if defined(__has_builtin)
#if __has_builtin(__builtin_amdgcn_fdot2)
#define HAVE_FDOT2 1
#endif
#endif
#ifndef HAVE_FDOT2
#define HAVE_FDOT2 0
#endif

__device__ __forceinline__ ushort f2bf(float f) {
  union { float f; uint32_t u; } v; v.f = f;
  uint32_t u = v.u;
  u += 0x7fffu + ((u >> 16) & 1u);   // round-to-nearest-even
  return (ushort)(u >> 16);
}

// ---------------------------------------------------------------------------
// prep: z<2 -> transpose x (b,c,hw) f32 -> xt (b,hw,c) bf16 (32x32 LDS tile)
//       z==2 -> convert qkv_w / proj_w to bf16
// ---------------------------------------------------------------------------
__global__ __launch_bounds__(256) void prep_k(
    const float* __restrict__ x, const float* __restrict__ qkv_w,
    const float* __restrict__ proj_w, ushort* __restrict__ xt,
    ushort* __restrict__ wq, ushort* __restrict__ wp) {
  if (blockIdx.z == 2) {
    int base = ((blockIdx.y * 98 + blockIdx.x) * 256 + threadIdx.x) * 2;
#pragma unroll
    for (int e = base; e < base + 2; ++e) {
      if (e < 768 * 256) wq[e] = f2bf(qkv_w[e]);
      else if (e < 768 * 256 + 256 * 256) {
        int e2 = e - 768 * 256;
        wp[e2] = f2bf(proj_w[e2]);
      }
    }
    return;
  }
  __shared__ float tile[32][33];
  const int hw0 = blockIdx.x * 32, c0 = blockIdx.y * 32, b = blockIdx.z;
  const int tx = threadIdx.x & 31, ty = threadIdx.x >> 5;
  const float* xb = x + ((size_t)b * CCH + c0) * HWT + hw0;
#pragma unroll
  for (int i = 0; i < 4; ++i) {
    int c = ty + i * 8;
    tile[c][tx] = xb[(size_t)c * HWT + tx];
  }
  __syncthreads();
  ushort* xo = xt + ((size_t)b * HWT + hw0) * CCH + c0;
#pragma unroll
  for (int i = 0; i < 4; ++i) {
    int hwl = ty + i * 8;
    xo[(size_t)hwl * CCH + tx] = f2bf(tile[tx][hwl]);
  }
}

// ---------------------------------------------------------------------------
// bf16 MFMA GEMM, (MI*32) x 128 tile, BK=32, 4 waves (2x2), 16x16x32 frags.
// A rows = M dim (weights), B rows = N dim (per-batch activation).
// MODE 0 (qkv, MI=4): epilogue -> fp16; q (bn,hw,d)*scale; v (bn,hw,d);
//   k TRANSPOSED as kT[(bn*8+d/4)][hw][4] for line-merged QK gathers.
// MODE 1 (proj, MI=2): epilogue -> fp32 out (b,o,hw) + bias. 200 blocks.
// ---------------------------------------------------------------------------
template <int MODE, int MI>
__global__ __launch_bounds__(256) void mfma_gemm_k(
    const ushort* __restrict__ A, int rowsA,
    const ushort* __restrict__ B, int rowsB,
    const float* __restrict__ biasv, void* __restrict__ outp) {
  __shared__ ushort Alds[MI * 32 * 32];
  __shared__ ushort Blds[128 * 32];

  const int t  = threadIdx.x;
  const int m0 = blockIdx.y * (MI * 32);
  const int n0 = blockIdx.x * 128;
  const int b  = blockIdx.z;

  const ushort* Ab = A;
  const ushort* Bb = B + (size_t)b * HWT * CCH;

  const int lane  = t & 63;
  const int wid   = t >> 6;
  const int wm    = (wid >> 1) * (MI * 16);
  const int wn    = (wid & 1) * 64;
  const int lrow  = lane & 15;
  const int cwant = lane >> 4;
  const int csw   = (cwant ^ ((lrow >> 1) & 3)) * 8;

  const int srow   = t >> 2;
  const int scslot = t & 3;
  const int wlds   = wid << 9;

  f32x4 acc[MI][4];
#pragma unroll
  for (int i = 0; i < MI; ++i)
#pragma unroll
    for (int j = 0; j < 4; ++j) acc[i][j] = (f32x4){0.f, 0.f, 0.f, 0.f};

  for (int k0 = 0; k0 < CCH; k0 += 32) {
    __syncthreads();
#pragma unroll
    for (int h = 0; h < MI / 2; ++h) {   // A halves
      const int lr   = srow + h * 64;
      const int csrc = (scslot ^ ((lr >> 1) & 3)) * 8;
      int ga = m0 + lr; ga = ga < rowsA ? ga : rowsA - 1;
      const ushort* gpa = Ab + (size_t)ga * CCH + k0 + csrc;
      ushort* lpa = Alds + h * 2048 + wlds;
      __builtin_amdgcn_global_load_lds(
          (const __attribute__((address_space(1))) void*)gpa,
          (__attribute__((address_space(3))) void*)lpa, 16, 0, 0);
    }
#pragma unroll
    for (int h = 0; h < 2; ++h) {        // B halves
      const int lr   = srow + h * 64;
      const int csrc = (scslot ^ ((lr >> 1) & 3)) * 8;
      int gb = n0 + lr; gb = gb < rowsB ? gb : rowsB - 1;
      const ushort* gpb = Bb + (size_t)gb * CCH + k0 + csrc;
      ushort* lpb = Blds + h * 2048 + wlds;
      __builtin_amdgcn_global_load_lds(
          (const __attribute__((address_space(1))) void*)gpb,
          (__attribute__((address_space(3))) void*)lpb, 16, 0, 0);
    }
    __syncthreads();

    short8 af[MI], bf[4];
#pragma unroll
    for (int mi = 0; mi < MI; ++mi)
      af[mi] = *(const short8*)&Alds[(wm + mi * 16 + lrow) * 32 + csw];
#pragma unroll
    for (int ni = 0; ni < 4; ++ni)
      bf[ni] = *(const short8*)&Blds[(wn + ni * 16 + lrow) * 32 + csw];
#pragma unroll
    for (int mi = 0; mi < MI; ++mi)
#pragma unroll
      for (int ni = 0; ni < 4; ++ni)
        acc[mi][ni] = __builtin_amdgcn_mfma_f32_16x16x32_bf16(
            af[mi], bf[ni], acc[mi][ni], 0, 0, 0);
  }

  const int row4 = (lane >> 4) * 4;
  if (MODE == 0) {
    _Float16* qh = (_Float16*)outp;
#pragma unroll
    for (int mi = 0; mi < MI; ++mi) {
      const int o0 = m0 + wm + mi * 16 + row4;   // quad of consecutive o
      const int t3 = o0 >> 8, c0 = o0 & 255;
      const int head = c0 >> 5, d0 = c0 & 31;
      const float sc = (t3 == 0) ? SCALE : 1.f;
      float bv[4];
#pragma unroll
      for (int r = 0; r < 4; ++r) bv[r] = biasv[o0 + r];
      if (t3 == 1) {
        // kT: ((bn*8 + d0/4) * HWT + hw) * 4
        _Float16* base = qh + (size_t)QKV_ELEMS +
                         ((size_t)(b * NH + head) * 8 + (d0 >> 2)) * (HWT * 4);
#pragma unroll
        for (int ni = 0; ni < 4; ++ni) {
          const int hw = n0 + wn + ni * 16 + lrow;
          if (hw < HWT) {
            half4v pack;
#pragma unroll
            for (int r = 0; r < 4; ++r)
              pack[r] = (_Float16)(acc[mi][ni][r] + bv[r]);
            *(half4v*)(base + (size_t)hw * 4) = pack;
          }
        }
      } else {
        _Float16* base = qh + (size_t)t3 * QKV_ELEMS +
                         (size_t)(b * NH + head) * HWT * 32 + d0;
#pragma unroll
        for (int ni = 0; ni < 4; ++ni) {
          const int hw = n0 + wn + ni * 16 + lrow;
          if (hw < HWT) {
            half4v pack;
#pragma unroll
            for (int r = 0; r < 4; ++r)
              pack[r] = (_Float16)((acc[mi][ni][r] + bv[r]) * sc);
            *(half4v*)(base + (size_t)hw * 32) = pack;
          }
        }
      }
    }
  } else {
    float* op = (float*)outp;
#pragma unroll
    for (int mi = 0; mi < MI; ++mi)
#pragma unroll
      for (int r = 0; r < 4; ++r) {
        const int o = m0 + wm + mi * 16 + row4 + r;
        const float bvv = biasv[o];
#pragma unroll
        for (int ni = 0; ni < 4; ++ni) {
          const int hw = n0 + wn + ni * 16 + lrow;
          if (hw < HWT)
            op[((size_t)b * CCH + o) * HWT + hw] = acc[mi][ni][r] + bvv;
        }
      }
  }
}

// ---------------------------------------------------------------------------
// Fused attention: block = 32 pixels x one (b,n); 256 threads; grid 1568.
// Phase A: wave-per-pixel QK; lane = neighbor j; K read from TRANSPOSED
//   kT[(d/4)][hw][4] -> lanes' s are consecutive -> ~7 lines per instr.
// Phase B: 8 threads/pixel PV (4 channels each) from row-major V (lanes of a
//   pixel share the V line -> merged). Out att_t (b,hw,c) bf16.
// ---------------------------------------------------------------------------
__global__ __launch_bounds__(256) void attn_fused_k(
    const _Float16* __restrict__ q_h, const _Float16* __restrict__ kt4,
    const _Float16* __restrict__ v_h, const float* __restrict__ relbias,
    ushort* __restrict__ att_t) {
  // bijective XCD swizzle (1568 % 8 == 0)
  const int id  = blockIdx.x;
  const int idx = (id & 7) * 196 + (id >> 3);
  const int bn  = idx / 98;
  const int px0 = (idx % 98) * 32;
  const int b = bn >> 3, n = bn & 7;

  __shared__ float bias_s[169];
  __shared__ uint32_t as_lds[32 * 49];

  const int tid = threadIdx.x;
  if (tid < 169) bias_s[tid] = relbias[tid * NH + n];
  __syncthreads();

  const int wid = tid >> 6, lane = tid & 63;
  const _Float16* ktb = kt4 + (size_t)bn * HWT * 32;  // (8 dq, HWT, 4)

#pragma unroll 2
  for (int pass = 0; pass < 8; ++pass) {
    const int pxl = pass * 4 + wid;
    const int px = px0 + pxl;
    const int h = px / WIMG, w = px % WIMG;
    int ph = h - 3; ph = ph < 0 ? 0 : (ph > 49 ? 49 : ph);
    int pw = w - 3; pw = pw < 0 ? 0 : (pw > 49 ? 49 : pw);
    const int l = ph * 50 + pw;
    const int bih = (h < 3) ? h : ((h < 53) ? 3 : h - 49);
    const int biw = (w < 3) ? w : ((w < 53) ? 3 : w - 49);
    const int bbase = bih * 13 + biw;

    union V64 { uint4 u[4]; half2v hv[16]; };
    V64 Q;   // wave-uniform broadcast load
    const uint4* qp = (const uint4*)(q_h + ((size_t)bn * HWT + px) * 32);
#pragma unroll
    for (int i = 0; i < 4; ++i) Q.u[i] = qp[i];

    if (lane < 49) {
      const int f = l * 49 + lane;
      const int sp = f / 2500;
      const int pos = f - sp * 2500;
      const int si = pos / 50;
      const int sj = pos - si * 50;
      const int s = (si + sp / 7) * WIMG + sj + sp % 7;

      float a0 = 0.f, a1 = 0.f, a2 = 0.f, a3 = 0.f;
#pragma unroll
      for (int dq = 0; dq < 8; ++dq) {
        union { half4v k4; half2v k2[2]; } K;
        K.k4 = *(const half4v*)(ktb + ((size_t)dq * HWT + s) * 4);
#if HAVE_FDOT2
        if (dq & 1) {
          a2 = __builtin_amdgcn_fdot2(K.k2[0], Q.hv[2 * dq], a2, false);
          a3 = __builtin_amdgcn_fdot2(K.k2[1], Q.hv[2 * dq + 1], a3, false);
        } else {
          a0 = __builtin_amdgcn_fdot2(K.k2[0], Q.hv[2 * dq], a0, false);
          a1 = __builtin_amdgcn_fdot2(K.k2[1], Q.hv[2 * dq + 1], a1, false);
        }
#else
        a0 += (float)K.k2[0][0] * (float)Q.hv[2*dq][0];
        a1 += (float)K.k2[0][1] * (float)Q.hv[2*dq][1];
        a2 += (float)K.k2[1][0] * (float)Q.hv[2*dq+1][0];
        a3 += (float)K.k2[1][1] * (float)Q.hv[2*dq+1][1];
#endif
      }
      float a = (a0 + a1) + (a2 + a3);
      a += bias_s[bbase + (lane / 7) * 13 + lane % 7];

      union { _Float16 hh; uint16_t us; } cv;
      cv.hh = (_Float16)a;
      as_lds[pxl * 49 + lane] = ((uint32_t)s << 16) | cv.us;
    }
  }
  __syncthreads();

  // Phase B: thread = (pixel, 4-channel group)
  const int pxb = tid >> 3, oc = tid & 7;
  const _Float16* vb = v_h + (size_t)bn * HWT * 32 + oc * 4;
  const uint32_t* arow = &as_lds[pxb * 49];

  float acc[4] = {0.f, 0.f, 0.f, 0.f};
#pragma unroll 7
  for (int j = 0; j < 49; ++j) {
    const uint32_t u = arow[j];
    union { uint16_t us; _Float16 hh; } cv;
    cv.us = (uint16_t)(u & 0xffffu);
    const float a = (float)cv.hh;
    const int s = (int)(u >> 16);
    const half4v v = *(const half4v*)(vb + (size_t)s * 32);
#pragma unroll
    for (int d = 0; d < 4; ++d) acc[d] += a * (float)v[d];
  }

  ushort tmp[4];
#pragma unroll
  for (int d = 0; d < 4; ++d) tmp[d] = f2bf(acc[d]);
  *(short4v*)(att_t + ((size_t)b * HWT + px0 + pxb) * CCH + n * 32 + oc * 4) =
      *(const short4v*)tmp;
}

// ---------------------------------------------------------------------------
extern "C" void kernel_launch(void* const* d_in, const int* in_sizes, int n_in,
                              void* d_out, int out_size, void* d_ws, size_t ws_size,
                              hipStream_t stream) {
  const float* x       = (const float*)d_in[0];
  const float* qkv_w   = (const float*)d_in[1];
  const float* qkv_b   = (const float*)d_in[2];
  const float* proj_w  = (const float*)d_in[3];
  const float* proj_b  = (const float*)d_in[4];
  const float* relbias = (const float*)d_in[5];
  float* out = (float*)d_out;

  char* wsb = (char*)d_ws;
  _Float16* qh  = (_Float16*)wsb;                      // q fp16 (bn,hw,d)
  _Float16* kt4 = qh + (size_t)QKV_ELEMS;              // kT fp16 (bn,d/4,hw,4)
  _Float16* vh  = qh + (size_t)2 * QKV_ELEMS;          // v fp16 (bn,hw,d)
  ushort*   xt  = (ushort*)(wsb + (size_t)3 * QKV_ELEMS * 2); // bf16 (b,hw,c)
  ushort*   wq  = xt + (size_t)QKV_ELEMS;              // bf16 768x256
  ushort*   wp  = wq + 768 * 256;                      // bf16 256x256
  ushort*   att_t = xt;  // alias: xt fully consumed by qkv GEMM first

  hipLaunchKernelGGL(prep_k, dim3(98, 8, 3), dim3(256), 0, stream,
                     x, qkv_w, proj_w, xt, wq, wp);
  // qkv: A=wq (m=o, 768 rows), B=xt (n=hw) -> fp16 q/kT/v
  hipLaunchKernelGGL((mfma_gemm_k<0, 4>), dim3(25, 6, 2), dim3(256), 0, stream,
                     wq, 768, xt, HWT, qkv_b, (void*)qh);
  hipLaunchKernelGGL(attn_fused_k, dim3(1568), dim3(256), 0, stream,
                     qh, kt4, vh, relbias, att_t);
  // proj: A=wp (m=o, 256 rows, BM=64), B=att_t (n=hw) -> fp32 out
  hipLaunchKernelGGL((mfma_gemm_k<1, 2>), dim3(25, 4, 2), dim3(256), 0, stream,
                     wp, 256, att_t, HWT, proj_b, (void*)out);
}